// Round 1
// baseline (169356.567 us; speedup 1.0000x reference)
//
#include <hip/hip_runtime.h>
#include <stdint.h>

typedef unsigned short ushort_t;
typedef __attribute__((ext_vector_type(8))) short short8;
typedef __attribute__((ext_vector_type(4))) float f32x4;

#define T_SEQ 3300

__device__ __forceinline__ ushort_t f2b(float f) {
  uint32_t u = __float_as_uint(f);
  u = (u + 0x7fffu + ((u >> 16) & 1u)) >> 16;
  return (ushort_t)u;
}
__device__ __forceinline__ float b2f(ushort_t b) {
  return __uint_as_float(((uint32_t)b) << 16);
}

// ---------------- prep: weight transpose/convert + barrier counter zero ----
__global__ void prep_kernel(const float* __restrict__ w_ih,
                            const float* __restrict__ fc1w,
                            const float* __restrict__ fc2w,
                            ushort_t* __restrict__ w_ihT,
                            ushort_t* __restrict__ fc1wb,
                            ushort_t* __restrict__ fc2wb,
                            int* __restrict__ ctr) {
  int i = blockIdx.x * 256 + threadIdx.x;
  if (i < 512 * 1536) {            // w_ihT[d][g] = w_ih[g][d], d<512 (one-hot rows)
    int d = i / 1536, g = i - d * 1536;
    w_ihT[i] = f2b(w_ih[g * 592 + d]);
  }
  int j = i - 512 * 1536;
  if (j >= 0 && j < 262144) fc1wb[j] = f2b(fc1w[j]);
  int k = j - 262144;
  if (k >= 0 && k < 262144) fc2wb[k] = f2b(fc2w[k]);
  int c = k - 262144;
  if (c >= 0 && c < 1024) ctr[c] = 0;
}

// ---------------- upsample: repeat+box-filter cascade, one block per (b,f) --
__global__ void upsample_kernel(const float* __restrict__ mels,
                                const float* __restrict__ k0,
                                const float* __restrict__ k1,
                                const float* __restrict__ k2,
                                float* __restrict__ mels_up) {
  __shared__ float s0[16];
  __shared__ float s1[80];
  __shared__ float s2[400];
  int bf = blockIdx.x;
  int b = bf / 80, f = bf - b * 80;
  int tid = threadIdx.x;  // 128
  float c0 = k0[0], c1 = k1[0], c2 = k2[0];
  if (tid < 16) s0[tid] = mels[(b * 80 + f) * 16 + tid];
  __syncthreads();
  if (tid < 80) {
    float a = 0.f;
    #pragma unroll
    for (int d = -5; d <= 5; ++d) {
      int w = tid + d;
      if (w >= 0 && w < 80) a += s0[w / 5];
    }
    s1[tid] = a * c0;
  }
  __syncthreads();
  for (int w = tid; w < 400; w += 128) {
    float a = 0.f;
    #pragma unroll
    for (int d = -5; d <= 5; ++d) {
      int u = w + d;
      if (u >= 0 && u < 400) a += s1[u / 5];
    }
    s2[w] = a * c1;
  }
  __syncthreads();
  for (int t = tid; t < T_SEQ; t += 128) {
    int wb = 550 + t;   // range [550, 3849]; wb+d in [539,3860] -> /11 < 400: no bounds needed
    float a = 0.f;
    #pragma unroll
    for (int d = -11; d <= 11; ++d) a += s2[(wb + d) / 11];
    mels_up[(b * 80 + f) * T_SEQ + t] = a * c2;
  }
}

// ---- 32-lane sum: DPP row_shr cascade (16) + shfl_xor 16. Valid on lane cc==15 (and 31).
__device__ __forceinline__ float red32(float x) {
  x += __uint_as_float((uint32_t)__builtin_amdgcn_update_dpp(0, (int)__float_as_uint(x), 0x111, 0xf, 0xf, true));
  x += __uint_as_float((uint32_t)__builtin_amdgcn_update_dpp(0, (int)__float_as_uint(x), 0x112, 0xf, 0xf, true));
  x += __uint_as_float((uint32_t)__builtin_amdgcn_update_dpp(0, (int)__float_as_uint(x), 0x114, 0xf, 0xf, true));
  x += __uint_as_float((uint32_t)__builtin_amdgcn_update_dpp(0, (int)__float_as_uint(x), 0x118, 0xf, 0xf, true));
  x += __shfl_xor(x, 16, 64);
  return x;
}

// ---------------- persistent GRU --------------------------------------------
// 256 blocks x 512 threads. Group = batch b (16 blocks); block j owns h dims [32j,32j+32).
// Weights register-resident: thread (cc=tid&31, rr=tid>>5) holds rows
// {gate*512 + 32j + 2rr + kk} x cols [20cc,20cc+20) of [W_hh | W_ih_mel | pad].
__global__ __launch_bounds__(512) void gru_kernel(
    const int* __restrict__ x,
    const float* __restrict__ mels_up,
    const float* __restrict__ w_ih,
    const float* __restrict__ w_hh,
    const float* __restrict__ b_ih,
    const float* __restrict__ b_hh,
    const ushort_t* __restrict__ w_ihT,
    float* __restrict__ ping,     // [2][16][512]
    int* __restrict__ ctr,        // [16][64]
    ushort_t* __restrict__ h_seq) // [16][3300][512] bf16
{
  int blk = blockIdx.x;
  int xcd = blk & 7, slot = blk >> 3;
  int b = (xcd << 1) | (slot >> 4);   // 2 groups per XCD (heuristic only; correctness agnostic)
  int j = slot & 15;
  int tid = threadIdx.x;
  int cc = tid & 31, rr = tid >> 5;

  __shared__ __align__(16) float v[640];    // [0,512)=h, [512,592)=mel, rest 0
  __shared__ float embs[96];

  if (tid < 48) v[592 + tid] = 0.f;

  // ---- load resident weights -------------------------------------------------
  float w[6][20];
  float wmel[2][3];
  float bsum[4], bihn[2], bhhn[2];
  #pragma unroll
  for (int q = 0; q < 6; ++q) {
    int gate = q >> 1, kk = q & 1;
    int g = gate * 512 + j * 32 + rr * 2 + kk;
    #pragma unroll
    for (int cl = 0; cl < 20; ++cl) {
      int col = cc * 20 + cl;
      float wv = 0.f;
      if (col < 512) wv = w_hh[g * 512 + col];
      else if (col < 592 && gate < 2) wv = w_ih[g * 592 + col]; // mel weights (r,z only)
      w[q][cl] = wv;
    }
  }
  #pragma unroll
  for (int kk = 0; kk < 2; ++kk) {
    int g = 1024 + j * 32 + rr * 2 + kk;
    #pragma unroll
    for (int ii = 0; ii < 3; ++ii) {
      int fidx = cc * 3 + ii;
      wmel[kk][ii] = (fidx < 80) ? w_ih[g * 592 + 512 + fidx] : 0.f;
    }
    bihn[kk] = b_ih[g];
    bhhn[kk] = b_hh[g];
  }
  #pragma unroll
  for (int q = 0; q < 4; ++q) {
    int gate = q >> 1, kk = q & 1;
    int g = gate * 512 + j * 32 + rr * 2 + kk;
    bsum[q] = b_ih[g] + b_hh[g];
  }

  int* myctr = ctr + b * 64;

  for (int t = 0; t < T_SEQ; ++t) {
    // ---- prefetch (independent of h) ----
    float melv = 0.f;
    if (tid < 80) melv = mels_up[(b * 80 + tid) * T_SEQ + t];
    float embv = 0.f;
    if (tid < 96) {
      int xv = x[b * T_SEQ + t];
      int gate = tid >> 5, kl = tid & 31;
      embv = b2f(w_ihT[xv * 1536 + gate * 512 + j * 32 + kl]);
    }
    // ---- wait for step t-1 (all 16 blocks of this group) ----
    if (t > 0) {
      int tgt = 16 * t;
      while (__hip_atomic_load(myctr, __ATOMIC_RELAXED, __HIP_MEMORY_SCOPE_AGENT) < tgt) {}
      __builtin_amdgcn_fence(__ATOMIC_ACQUIRE, "agent");
    }
    // ---- stage v = [h | mel] and emb into LDS ----
    if (tid < 128) {
      f32x4 hv = {0.f, 0.f, 0.f, 0.f};
      if (t > 0) hv = *(const f32x4*)&ping[((t & 1) * 16 + b) * 512 + tid * 4];
      *(f32x4*)&v[tid * 4] = hv;
    }
    if (tid < 80) v[512 + tid] = melv;
    if (tid < 96) embs[tid] = embv;
    __syncthreads();

    // ---- matvec: acc[q] = sum_cols v[col]*W[row(q)][col] ----
    float hv20[20];
    #pragma unroll
    for (int s = 0; s < 5; ++s) {
      f32x4 t4 = *(const f32x4*)&v[cc * 20 + s * 4];
      hv20[s * 4 + 0] = t4[0]; hv20[s * 4 + 1] = t4[1];
      hv20[s * 4 + 2] = t4[2]; hv20[s * 4 + 3] = t4[3];
    }
    float a0 = 0.f, a1 = 0.f, a2 = 0.f, a3 = 0.f, a4 = 0.f, a5 = 0.f;
    #pragma unroll
    for (int cl = 0; cl < 20; ++cl) {
      float hvv = hv20[cl];
      a0 += hvv * w[0][cl]; a1 += hvv * w[1][cl];
      a2 += hvv * w[2][cl]; a3 += hvv * w[3][cl];
      a4 += hvv * w[4][cl]; a5 += hvv * w[5][cl];
    }
    float am0 = 0.f, am1 = 0.f;   // n-gate x-side mel part (kept separate from h-side)
    #pragma unroll
    for (int ii = 0; ii < 3; ++ii) {
      float mv = v[512 + cc * 3 + ii];
      am0 += mv * wmel[0][ii]; am1 += mv * wmel[1][ii];
    }
    float r0 = red32(a0), r1 = red32(a1), r2 = red32(a2);
    float r3 = red32(a3), r4 = red32(a4), r5 = red32(a5);
    float rm0 = red32(am0), rm1 = red32(am1);

    if (cc == 15) {
      #pragma unroll
      for (int kk = 0; kk < 2; ++kk) {
        float sr  = kk ? r1 : r0;
        float sz  = kk ? r3 : r2;
        float sn  = kk ? r5 : r4;
        float smn = kk ? rm1 : rm0;
        int k = rr * 2 + kk;
        float ar = embs[k] + sr + bsum[0 + kk];
        float az = embs[32 + k] + sz + bsum[2 + kk];
        float rg = 1.f / (1.f + __expf(-ar));
        float zg = 1.f / (1.f + __expf(-az));
        float xn = embs[64 + k] + smn + bihn[kk];
        float hn = sn + bhhn[kk];
        float na = xn + rg * hn;
        float e2 = __expf(2.f * na);
        float ng = 1.f - 2.f / (e2 + 1.f);   // tanh
        float hp = v[j * 32 + k];
        float hnew = (1.f - zg) * ng + zg * hp;
        ping[(((t + 1) & 1) * 16 + b) * 512 + j * 32 + k] = hnew;
        h_seq[(size_t)(b * T_SEQ + t) * 512 + j * 32 + k] = f2b(hnew);
      }
    }
    __threadfence();          // device-scope release of h writes
    __syncthreads();          // all compute/stores of step t done
    if (tid == 15) __hip_atomic_fetch_add(myctr, 1, __ATOMIC_RELAXED, __HIP_MEMORY_SCOPE_AGENT);
  }
}

// ---------------- fused head: relu(h*fc1^T+b1)*fc2^T+b2 via bf16 MFMA -------
__global__ __launch_bounds__(512) void head_kernel(
    const ushort_t* __restrict__ h_seq,
    const ushort_t* __restrict__ fc1w,   // [n][k] bf16
    const ushort_t* __restrict__ fc2w,   // [n][k] bf16
    const float* __restrict__ fc1b,
    const float* __restrict__ fc2b,
    float* __restrict__ out) {
  __shared__ __align__(16) ushort_t h1[64 * 512];
  int blk = blockIdx.x;          // 825 blocks, 64 rows each
  int tid = threadIdx.x;
  int w = tid >> 6, l = tid & 63;
  int lm = l & 15, lq = l >> 4;
  int mt = w & 3;                // m-tile within the 64-row block
  int nb = (w >> 2) * 256;       // this wave's n-range
  int m0 = blk * 64;

  // stage 1: h1 = relu(h*fc1^T + b1)
  f32x4 acc[16];
  #pragma unroll
  for (int i = 0; i < 16; ++i) acc[i] = (f32x4){0.f, 0.f, 0.f, 0.f};
  const ushort_t* arow = h_seq + (size_t)(m0 + mt * 16 + lm) * 512;
  for (int kt = 0; kt < 16; ++kt) {
    short8 a = *(const short8*)(arow + kt * 32 + lq * 8);
    #pragma unroll
    for (int nt = 0; nt < 16; ++nt) {
      short8 bb = *(const short8*)(fc1w + (size_t)(nb + nt * 16 + lm) * 512 + kt * 32 + lq * 8);
      acc[nt] = __builtin_amdgcn_mfma_f32_16x16x32_bf16(a, bb, acc[nt], 0, 0, 0);
    }
  }
  #pragma unroll
  for (int nt = 0; nt < 16; ++nt) {
    int n = nb + nt * 16 + lm;
    float bias = fc1b[n];
    #pragma unroll
    for (int r = 0; r < 4; ++r) {
      int m = mt * 16 + lq * 4 + r;
      float vv = acc[nt][r] + bias;
      vv = fmaxf(vv, 0.f);
      h1[m * 512 + n] = f2b(vv);
    }
  }
  __syncthreads();
  // stage 2: out = h1*fc2^T + b2
  f32x4 acc2[16];
  #pragma unroll
  for (int i = 0; i < 16; ++i) acc2[i] = (f32x4){0.f, 0.f, 0.f, 0.f};
  for (int kt = 0; kt < 16; ++kt) {
    short8 a = *(const short8*)&h1[(mt * 16 + lm) * 512 + kt * 32 + lq * 8];
    #pragma unroll
    for (int nt = 0; nt < 16; ++nt) {
      short8 bb = *(const short8*)(fc2w + (size_t)(nb + nt * 16 + lm) * 512 + kt * 32 + lq * 8);
      acc2[nt] = __builtin_amdgcn_mfma_f32_16x16x32_bf16(a, bb, acc2[nt], 0, 0, 0);
    }
  }
  #pragma unroll
  for (int nt = 0; nt < 16; ++nt) {
    int n = nb + nt * 16 + lm;
    float bias = fc2b[n];
    #pragma unroll
    for (int r = 0; r < 4; ++r) {
      int m = mt * 16 + lq * 4 + r;
      out[(size_t)(m0 + m) * 512 + n] = acc2[nt][r] + bias;
    }
  }
}

// ---------------- launch -----------------------------------------------------
extern "C" void kernel_launch(void* const* d_in, const int* in_sizes, int n_in,
                              void* d_out, int out_size, void* d_ws, size_t ws_size,
                              hipStream_t stream) {
  (void)in_sizes; (void)n_in; (void)out_size; (void)ws_size;
  const int*   x    = (const int*)d_in[0];
  const float* mels = (const float*)d_in[1];
  const float* k0   = (const float*)d_in[2];
  const float* k1   = (const float*)d_in[3];
  const float* k2   = (const float*)d_in[4];
  const float* w_ih = (const float*)d_in[5];
  const float* w_hh = (const float*)d_in[6];
  const float* b_ih = (const float*)d_in[7];
  const float* b_hh = (const float*)d_in[8];
  const float* fc1w = (const float*)d_in[9];
  const float* fc1b = (const float*)d_in[10];
  const float* fc2w = (const float*)d_in[11];
  const float* fc2b = (const float*)d_in[12];

  char* ws = (char*)d_ws;
  float*    mels_up = (float*)(ws + 0);           // 16*80*3300*4  = 16,896,000
  ushort_t* h_seq   = (ushort_t*)(ws + 16896000); // 16*3300*512*2 = 54,067,200
  ushort_t* w_ihT   = (ushort_t*)(ws + 70963200); // 512*1536*2    =  1,572,864
  ushort_t* fc1wb   = (ushort_t*)(ws + 72536064); // 512*512*2     =    524,288
  ushort_t* fc2wb   = (ushort_t*)(ws + 73060352); // 512*512*2     =    524,288
  float*    ping    = (float*)(ws + 73584640);    // 2*16*512*4    =     65,536
  int*      ctr     = (int*)(ws + 73650176);      // 16*64*4       =      4,096

  prep_kernel<<<5124, 256, 0, stream>>>(w_ih, fc1w, fc2w, w_ihT, fc1wb, fc2wb, ctr);
  upsample_kernel<<<1280, 128, 0, stream>>>(mels, k0, k1, k2, mels_up);
  gru_kernel<<<256, 512, 0, stream>>>(x, mels_up, w_ih, w_hh, b_ih, b_hh, w_ihT,
                                      ping, ctr, h_seq);
  head_kernel<<<825, 512, 0, stream>>>(h_seq, fc1wb, fc2wb, fc1b, fc2b, (float*)d_out);
}

// Round 2
// 6765.954 us; speedup vs baseline: 25.0307x; 25.0307x over previous
//
#include <hip/hip_runtime.h>
#include <stdint.h>

typedef unsigned short ushort_t;
typedef unsigned long long u64;
typedef __attribute__((ext_vector_type(8))) short short8;
typedef __attribute__((ext_vector_type(4))) float f32x4;

#define T_SEQ 3300
#define SENT 0x7FC00001u
#define SENTPAIR 0x7FC000017FC00001ull

__device__ __forceinline__ ushort_t f2b(float f) {
  uint32_t u = __float_as_uint(f);
  u = (u + 0x7fffu + ((u >> 16) & 1u)) >> 16;
  return (ushort_t)u;
}
__device__ __forceinline__ float b2f(ushort_t b) {
  return __uint_as_float(((uint32_t)b) << 16);
}

// ---------------- prep: weight transpose/convert + ring sentinel init -------
__global__ void prep_kernel(const float* __restrict__ w_ih,
                            const float* __restrict__ fc1w,
                            const float* __restrict__ fc2w,
                            ushort_t* __restrict__ w_ihT,
                            ushort_t* __restrict__ fc1wb,
                            ushort_t* __restrict__ fc2wb,
                            uint32_t* __restrict__ h_ring) {
  int i = blockIdx.x * 256 + threadIdx.x;
  if (i < 512 * 1536) {            // w_ihT[d][g] = w_ih[g][d], d<512 (one-hot rows)
    int d = i / 1536, g = i - d * 1536;
    w_ihT[i] = f2b(w_ih[g * 592 + d]);
  }
  int j = i - 512 * 1536;
  if (j >= 0 && j < 262144) fc1wb[j] = f2b(fc1w[j]);
  int k = j - 262144;
  if (k >= 0 && k < 262144) fc2wb[k] = f2b(fc2w[k]);
  int c = k - 262144;
  if (c >= 0 && c < 131072) {
    // sentinel must be visible at the coherence point (gru reads bypass L2),
    // so write it with a cache-bypassing relaxed agent atomic store.
    __hip_atomic_store(&h_ring[c], SENT, __ATOMIC_RELAXED, __HIP_MEMORY_SCOPE_AGENT);
  }
}

// ---------------- upsample: repeat+box-filter cascade, one block per (b,f) --
__global__ void upsample_kernel(const float* __restrict__ mels,
                                const float* __restrict__ k0,
                                const float* __restrict__ k1,
                                const float* __restrict__ k2,
                                float* __restrict__ mels_up) {
  __shared__ float s0[16];
  __shared__ float s1[80];
  __shared__ float s2[400];
  int bf = blockIdx.x;
  int b = bf / 80, f = bf - b * 80;
  int tid = threadIdx.x;  // 128
  float c0 = k0[0], c1 = k1[0], c2 = k2[0];
  if (tid < 16) s0[tid] = mels[(b * 80 + f) * 16 + tid];
  __syncthreads();
  if (tid < 80) {
    float a = 0.f;
    #pragma unroll
    for (int d = -5; d <= 5; ++d) {
      int w = tid + d;
      if (w >= 0 && w < 80) a += s0[w / 5];
    }
    s1[tid] = a * c0;
  }
  __syncthreads();
  for (int w = tid; w < 400; w += 128) {
    float a = 0.f;
    #pragma unroll
    for (int d = -5; d <= 5; ++d) {
      int u = w + d;
      if (u >= 0 && u < 400) a += s1[u / 5];
    }
    s2[w] = a * c1;
  }
  __syncthreads();
  for (int t = tid; t < T_SEQ; t += 128) {
    int wb = 550 + t;   // wb+d in [539,3860] -> /11 < 400: no bounds needed
    float a = 0.f;
    #pragma unroll
    for (int d = -11; d <= 11; ++d) a += s2[(wb + d) / 11];
    mels_up[(b * 80 + f) * T_SEQ + t] = a * c2;
  }
}

// ---- 32-lane sum: DPP row_shr cascade (16) + shfl_xor 16. Valid on lane cc==15 (and 31).
__device__ __forceinline__ float red32(float x) {
  x += __uint_as_float((uint32_t)__builtin_amdgcn_update_dpp(0, (int)__float_as_uint(x), 0x111, 0xf, 0xf, true));
  x += __uint_as_float((uint32_t)__builtin_amdgcn_update_dpp(0, (int)__float_as_uint(x), 0x112, 0xf, 0xf, true));
  x += __uint_as_float((uint32_t)__builtin_amdgcn_update_dpp(0, (int)__float_as_uint(x), 0x114, 0xf, 0xf, true));
  x += __uint_as_float((uint32_t)__builtin_amdgcn_update_dpp(0, (int)__float_as_uint(x), 0x118, 0xf, 0xf, true));
  x += __shfl_xor(x, 16, 64);
  return x;
}

// ---------------- persistent GRU --------------------------------------------
// 256 blocks x 512 threads. Group = batch b (16 blocks); block j owns h dims [32j,32j+32).
// Cross-block h exchange: 16-slot ring h_ring[slot][b][512] (fp32), written/read with
// RELAXED AGENT atomics (sc0 sc1 cache-bypassing ops, NO buffer_wbl2/buffer_inv).
// Readiness = data != NaN-sentinel; slot re-armed to sentinel 9 steps before reuse.
__global__ __launch_bounds__(512) void gru_kernel(
    const int* __restrict__ x,
    const float* __restrict__ mels_up,
    const float* __restrict__ w_ih,
    const float* __restrict__ w_hh,
    const float* __restrict__ b_ih,
    const float* __restrict__ b_hh,
    const ushort_t* __restrict__ w_ihT,
    uint32_t* __restrict__ h_ring,  // [16][16][512] fp32 bits
    ushort_t* __restrict__ h_seq)   // [16][3300][512] bf16
{
  int blk = blockIdx.x;
  int xcd = blk & 7, slot = blk >> 3;
  int b = (xcd << 1) | (slot >> 4);   // XCD-spread heuristic only; correctness agnostic
  int j = slot & 15;
  int tid = threadIdx.x;
  int cc = tid & 31, rr = tid >> 5;

  __shared__ __align__(16) float v[640];    // [0,512)=h, [512,592)=mel, rest 0
  __shared__ float embs[96];

  if (tid < 48) v[592 + tid] = 0.f;

  // ---- load resident weights ----
  float w[6][20];
  float wmel[2][3];
  float bsum[4], bihn[2], bhhn[2];
  #pragma unroll
  for (int q = 0; q < 6; ++q) {
    int gate = q >> 1, kk = q & 1;
    int g = gate * 512 + j * 32 + rr * 2 + kk;
    #pragma unroll
    for (int cl = 0; cl < 20; ++cl) {
      int col = cc * 20 + cl;
      float wv = 0.f;
      if (col < 512) wv = w_hh[g * 512 + col];
      else if (col < 592 && gate < 2) wv = w_ih[g * 592 + col]; // mel weights (r,z only)
      w[q][cl] = wv;
    }
  }
  #pragma unroll
  for (int kk = 0; kk < 2; ++kk) {
    int g = 1024 + j * 32 + rr * 2 + kk;
    #pragma unroll
    for (int ii = 0; ii < 3; ++ii) {
      int fidx = cc * 3 + ii;
      wmel[kk][ii] = (fidx < 80) ? w_ih[g * 592 + 512 + fidx] : 0.f;
    }
    bihn[kk] = b_ih[g];
    bhhn[kk] = b_hh[g];
  }
  #pragma unroll
  for (int q = 0; q < 4; ++q) {
    int gate = q >> 1, kk = q & 1;
    int g = gate * 512 + j * 32 + rr * 2 + kk;
    bsum[q] = b_ih[g] + b_hh[g];
  }

  for (int t = 0; t < T_SEQ; ++t) {
    // ---- prefetch (independent of h; plain cached loads) ----
    float melv = 0.f;
    if (tid < 80) melv = mels_up[(b * 80 + tid) * T_SEQ + t];
    float embv = 0.f;
    if (tid < 96) {
      int xv = x[b * T_SEQ + t];
      int gate = tid >> 5, kl = tid & 31;
      embv = b2f(w_ihT[xv * 1536 + gate * 512 + j * 32 + kl]);
    }
    // ---- poll h_{t-1} directly on data (sentinel = not ready) ----
    u64 q0 = 0, q1 = 0;
    if (t > 0 && tid < 128) {
      int rslot = (t - 1) & 15;
      const u64* src = (const u64*)&h_ring[((rslot * 16 + b) * 512) + tid * 4];
      for (;;) {
        q0 = __hip_atomic_load(src,     __ATOMIC_RELAXED, __HIP_MEMORY_SCOPE_AGENT);
        q1 = __hip_atomic_load(src + 1, __ATOMIC_RELAXED, __HIP_MEMORY_SCOPE_AGENT);
        if (((uint32_t)q0) != SENT && ((uint32_t)(q0 >> 32)) != SENT &&
            ((uint32_t)q1) != SENT && ((uint32_t)(q1 >> 32)) != SENT) break;
      }
    }
    // ---- stage v = [h | mel] and emb into LDS ----
    if (tid < 128) {
      ((u64*)v)[tid * 2]     = q0;   // t==0 -> zeros
      ((u64*)v)[tid * 2 + 1] = q1;
    }
    if (tid < 80) v[512 + tid] = melv;
    if (tid < 96) embs[tid] = embv;
    __syncthreads();

    // ---- matvec: acc[q] = sum_cols v[col]*W[row(q)][col] ----
    float hv20[20];
    #pragma unroll
    for (int s = 0; s < 5; ++s) {
      f32x4 t4 = *(const f32x4*)&v[cc * 20 + s * 4];
      hv20[s * 4 + 0] = t4[0]; hv20[s * 4 + 1] = t4[1];
      hv20[s * 4 + 2] = t4[2]; hv20[s * 4 + 3] = t4[3];
    }
    float a0 = 0.f, a1 = 0.f, a2 = 0.f, a3 = 0.f, a4 = 0.f, a5 = 0.f;
    #pragma unroll
    for (int cl = 0; cl < 20; ++cl) {
      float hvv = hv20[cl];
      a0 += hvv * w[0][cl]; a1 += hvv * w[1][cl];
      a2 += hvv * w[2][cl]; a3 += hvv * w[3][cl];
      a4 += hvv * w[4][cl]; a5 += hvv * w[5][cl];
    }
    float am0 = 0.f, am1 = 0.f;   // n-gate x-side mel part (kept separate from h-side)
    #pragma unroll
    for (int ii = 0; ii < 3; ++ii) {
      float mv = v[512 + cc * 3 + ii];
      am0 += mv * wmel[0][ii]; am1 += mv * wmel[1][ii];
    }
    float r0 = red32(a0), r1 = red32(a1), r2 = red32(a2);
    float r3 = red32(a3), r4 = red32(a4), r5 = red32(a5);
    float rm0 = red32(am0), rm1 = red32(am1);

    if (cc == 15) {
      float hn2[2];
      #pragma unroll
      for (int kk = 0; kk < 2; ++kk) {
        float sr  = kk ? r1 : r0;
        float sz  = kk ? r3 : r2;
        float sn  = kk ? r5 : r4;
        float smn = kk ? rm1 : rm0;
        int k = rr * 2 + kk;
        float ar = embs[k] + sr + bsum[0 + kk];
        float az = embs[32 + k] + sz + bsum[2 + kk];
        float rg = 1.f / (1.f + __expf(-ar));
        float zg = 1.f / (1.f + __expf(-az));
        float xn = embs[64 + k] + smn + bihn[kk];
        float hn = sn + bhhn[kk];
        float na = xn + rg * hn;
        float e2 = __expf(2.f * na);
        float ng = 1.f - 2.f / (e2 + 1.f);   // tanh
        float hp = v[j * 32 + k];
        hn2[kk] = (1.f - zg) * ng + zg * hp;
      }
      // publish h_t: cache-bypassing relaxed agent store (no cache maintenance)
      int wslot = t & 15;
      u64 pk = ((u64)__float_as_uint(hn2[1]) << 32) | (u64)__float_as_uint(hn2[0]);
      u64* dst = (u64*)&h_ring[((wslot * 16 + b) * 512) + j * 32 + rr * 2];
      __hip_atomic_store(dst, pk, __ATOMIC_RELAXED, __HIP_MEMORY_SCOPE_AGENT);
      // re-arm slot t+8 (next written at t+8, last read at t-7: safe margin;
      // same-thread same-address ordering + per-step vmcnt drain at barrier)
      int aslot = (t + 8) & 15;
      u64* adst = (u64*)&h_ring[((aslot * 16 + b) * 512) + j * 32 + rr * 2];
      __hip_atomic_store(adst, SENTPAIR, __ATOMIC_RELAXED, __HIP_MEMORY_SCOPE_AGENT);
      // h_seq for the head (plain cached store; kernel boundary makes it visible)
      uint32_t hb = (uint32_t)f2b(hn2[0]) | ((uint32_t)f2b(hn2[1]) << 16);
      *(uint32_t*)&h_seq[(size_t)(b * T_SEQ + t) * 512 + j * 32 + rr * 2] = hb;
    }
    __syncthreads();   // v reused next step; also drains stores (vmcnt(0) at barrier)
  }
}

// ---------------- fused head: relu(h*fc1^T+b1)*fc2^T+b2 via bf16 MFMA -------
__global__ __launch_bounds__(512) void head_kernel(
    const ushort_t* __restrict__ h_seq,
    const ushort_t* __restrict__ fc1w,   // [n][k] bf16
    const ushort_t* __restrict__ fc2w,   // [n][k] bf16
    const float* __restrict__ fc1b,
    const float* __restrict__ fc2b,
    float* __restrict__ out) {
  __shared__ __align__(16) ushort_t h1[64 * 512];
  int blk = blockIdx.x;          // 825 blocks, 64 rows each
  int tid = threadIdx.x;
  int w = tid >> 6, l = tid & 63;
  int lm = l & 15, lq = l >> 4;
  int mt = w & 3;                // m-tile within the 64-row block
  int nb = (w >> 2) * 256;       // this wave's n-range
  int m0 = blk * 64;

  // stage 1: h1 = relu(h*fc1^T + b1)
  f32x4 acc[16];
  #pragma unroll
  for (int i = 0; i < 16; ++i) acc[i] = (f32x4){0.f, 0.f, 0.f, 0.f};
  const ushort_t* arow = h_seq + (size_t)(m0 + mt * 16 + lm) * 512;
  for (int kt = 0; kt < 16; ++kt) {
    short8 a = *(const short8*)(arow + kt * 32 + lq * 8);
    #pragma unroll
    for (int nt = 0; nt < 16; ++nt) {
      short8 bb = *(const short8*)(fc1w + (size_t)(nb + nt * 16 + lm) * 512 + kt * 32 + lq * 8);
      acc[nt] = __builtin_amdgcn_mfma_f32_16x16x32_bf16(a, bb, acc[nt], 0, 0, 0);
    }
  }
  #pragma unroll
  for (int nt = 0; nt < 16; ++nt) {
    int n = nb + nt * 16 + lm;
    float bias = fc1b[n];
    #pragma unroll
    for (int r = 0; r < 4; ++r) {
      int m = mt * 16 + lq * 4 + r;
      float vv = acc[nt][r] + bias;
      vv = fmaxf(vv, 0.f);
      h1[m * 512 + n] = f2b(vv);
    }
  }
  __syncthreads();
  // stage 2: out = h1*fc2^T + b2
  f32x4 acc2[16];
  #pragma unroll
  for (int i = 0; i < 16; ++i) acc2[i] = (f32x4){0.f, 0.f, 0.f, 0.f};
  for (int kt = 0; kt < 16; ++kt) {
    short8 a = *(const short8*)&h1[(mt * 16 + lm) * 512 + kt * 32 + lq * 8];
    #pragma unroll
    for (int nt = 0; nt < 16; ++nt) {
      short8 bb = *(const short8*)(fc2w + (size_t)(nb + nt * 16 + lm) * 512 + kt * 32 + lq * 8);
      acc2[nt] = __builtin_amdgcn_mfma_f32_16x16x32_bf16(a, bb, acc2[nt], 0, 0, 0);
    }
  }
  #pragma unroll
  for (int nt = 0; nt < 16; ++nt) {
    int n = nb + nt * 16 + lm;
    float bias = fc2b[n];
    #pragma unroll
    for (int r = 0; r < 4; ++r) {
      int m = mt * 16 + lq * 4 + r;
      out[(size_t)(m0 + m) * 512 + n] = acc2[nt][r] + bias;
    }
  }
}

// ---------------- launch -----------------------------------------------------
extern "C" void kernel_launch(void* const* d_in, const int* in_sizes, int n_in,
                              void* d_out, int out_size, void* d_ws, size_t ws_size,
                              hipStream_t stream) {
  (void)in_sizes; (void)n_in; (void)out_size; (void)ws_size;
  const int*   x    = (const int*)d_in[0];
  const float* mels = (const float*)d_in[1];
  const float* k0   = (const float*)d_in[2];
  const float* k1   = (const float*)d_in[3];
  const float* k2   = (const float*)d_in[4];
  const float* w_ih = (const float*)d_in[5];
  const float* w_hh = (const float*)d_in[6];
  const float* b_ih = (const float*)d_in[7];
  const float* b_hh = (const float*)d_in[8];
  const float* fc1w = (const float*)d_in[9];
  const float* fc1b = (const float*)d_in[10];
  const float* fc2w = (const float*)d_in[11];
  const float* fc2b = (const float*)d_in[12];

  char* ws = (char*)d_ws;
  float*    mels_up = (float*)(ws + 0);           // 16*80*3300*4  = 16,896,000
  ushort_t* h_seq   = (ushort_t*)(ws + 16896000); // 16*3300*512*2 = 54,067,200
  ushort_t* w_ihT   = (ushort_t*)(ws + 70963200); // 512*1536*2    =  1,572,864
  ushort_t* fc1wb   = (ushort_t*)(ws + 72536064); // 512*512*2     =    524,288
  ushort_t* fc2wb   = (ushort_t*)(ws + 73060352); // 512*512*2     =    524,288
  uint32_t* h_ring  = (uint32_t*)(ws + 73584640); // 16*16*512*4   =    524,288

  prep_kernel<<<5632, 256, 0, stream>>>(w_ih, fc1w, fc2w, w_ihT, fc1wb, fc2wb, h_ring);
  upsample_kernel<<<1280, 128, 0, stream>>>(mels, k0, k1, k2, mels_up);
  gru_kernel<<<256, 512, 0, stream>>>(x, mels_up, w_ih, w_hh, b_ih, b_hh, w_ihT,
                                      h_ring, h_seq);
  head_kernel<<<825, 512, 0, stream>>>(h_seq, fc1wb, fc2wb, fc1b, fc2b, (float*)d_out);
}